// Round 9
// baseline (150.748 us; speedup 1.0000x reference)
//
#include <hip/hip_runtime.h>
#include <hip/hip_bf16.h>
#include <math.h>

#define ICH   3
#define OCH   16
#define ID    18
#define IH    34
#define IW    34
#define OD    16
#define OH    32
#define OW    32
#define NB    128
#define SPATIAL  (OD * OH * OW)     // 16384 per (b,c)
#define EPSV     1e-5f

// LDS staging geometry (conv): half-slice = 18 input rows x 9 planes,
// rows padded to 36 elems (72B, == 0 mod 8). 4 phase copies.
#define SROWS  18
#define RPAD   36
#define CELEMS (9 * SROWS * RPAD)        // 5832 fp16 per copy
#define SLOT   11680                     // copy stride bytes (11664 + pad)

typedef __fp16 fp16x2 __attribute__((ext_vector_type(2)));
typedef _Float16 half8v __attribute__((ext_vector_type(8)));
typedef float f32x4 __attribute__((ext_vector_type(4)));

// Budget (R3-R8): non-MFMA MAC floor ~40us busy (4 formulations agree);
// R8 MFMA conv = 70us but BOTH pipes idle -> cost is 384 ds_read_u16/wave
// + 4.3M bank conflicts. This round: same MFMA, gathers as ds_read_b64
// row-quads (64 reads/wave, 6x fewer) via 4 phase-shifted LDS copies.

// Pre-pass: wB2[m][c][kg][j] fp16: slot (m,kg,q=j>>2,jw=j&3) <-> row
// r = m*8+kg*2+q (= ic*9+kd*3+kh), kw = jw; zero for jw==3 or r>=27.
__global__ void transpose_w_kernel(const float* __restrict__ cw,
                                   unsigned short* __restrict__ wB2) {
    const int i = blockIdx.x * 256 + threadIdx.x;   // 0..2047
    if (i < 2048) {
        const int m  = i >> 9;
        const int c  = (i >> 5) & 15;
        const int kg = (i >> 3) & 3;
        const int j  = i & 7;
        const int r  = m * 8 + kg * 2 + (j >> 2);
        const int jw = j & 3;
        const float f = (jw < 3 && r < 27) ? cw[c * 81 + r * 3 + jw] : 0.0f;
        union { __fp16 h; unsigned short u; } uu;
        uu.h = (__fp16)f;
        wB2[i] = uu.u;
    }
}

// ===== conv v15: MFMA + wide gathers. One (b,d,half) 16-row slice per
// block (grid 4096), 4 waves x 4 rows. Lane: channel=ml=lane&15, kg=lane>>4.
// A-gather: per mfma m, 2 quads (rows kg*2+{0,1}) via ds_read_b64 from the
// phase copy s=ml&3 (base == (8-2s) mod 8 -> byte base+2ml == 0 mod 8).
// (th,hf) walked via immediate offsets th*72+hf*32. C/D map & slot symmetry
// validated by R8 (passed). Do NOT: u16 gathers (R8: LDS-pipe bound),
// pk_fma_f16 (R6), occupancy pushes (R4), channel-last y (R2).
__global__ __launch_bounds__(256, 2) void conv_stats_kernel(
    const float* __restrict__ x, const unsigned short* __restrict__ wB2,
    const float* __restrict__ cb, const float* __restrict__ mult,
    unsigned short* __restrict__ y, float* __restrict__ stats)
{
    __shared__ unsigned long long lds64[(4 * SLOT) / 8];   // 46720 B
    __shared__ float wsum[4][OCH], wsq[4][OCH];
    char* L = (char*)lds64;

    const int blk  = blockIdx.x;           // 0..4095
    const int b    = blk >> 5;
    const int d    = (blk >> 1) & 15;
    const int half = blk & 1;
    const int h0   = half * 16;
    const int tid  = threadIdx.x;

    // ---- stage: 9 planes x 18 rows, cols 0..33 (+2 zero pad) -> 4 copies ----
    // chunk = (p, lr, cg): 4 fp16 at byte (p*18+lr)*72 + cg*8 within a copy.
    for (int c0 = tid; c0 < 9 * SROWS * 9; c0 += 256) {
        const int p  = c0 / 162;
        const int rm = c0 - p * 162;
        const int lr = rm / 9;
        const int cg = rm - lr * 9;
        const int ic = p / 3, kd = p - ic * 3;
        const float* gp = x + ((size_t)(b * ICH + ic) * ID + (d + kd)) * (IH * IW)
                        + (size_t)(h0 + lr) * IW;
        float f0, f1, f2, f3;
        if (cg < 8) {
            const float2 a = *(const float2*)(gp + cg * 4);
            const float2 bq = *(const float2*)(gp + cg * 4 + 2);
            f0 = a.x; f1 = a.y; f2 = bq.x; f3 = bq.y;
        } else {
            const float2 a = *(const float2*)(gp + 32);
            f0 = a.x; f1 = a.y; f2 = 0.0f; f3 = 0.0f;   // cols 34,35 never used
        }
        union { fp16x2 h; unsigned int u; } lo, hi;
        lo.h = __builtin_amdgcn_cvt_pkrtz(f0, f1);
        hi.h = __builtin_amdgcn_cvt_pkrtz(f2, f3);
        const int wb = (p * SROWS + lr) * 72 + cg * 8;
        // copy0 (phase 0): b64
        { uint2 v; v.x = lo.u; v.y = hi.u;
          *(uint2*)(L + 0 * SLOT + 0 + wb) = v; }
        // copy2 (phase 4): 2x b32
        { unsigned int* p2 = (unsigned int*)(L + 2 * SLOT + 4 + wb);
          p2[0] = lo.u; p2[1] = hi.u; }
        // copies 1,3 (phase 6,2): 4x u16
        { unsigned short* p1 = (unsigned short*)(L + 1 * SLOT + 6 + wb);
          p1[0] = (unsigned short)(lo.u & 0xffff); p1[1] = (unsigned short)(lo.u >> 16);
          p1[2] = (unsigned short)(hi.u & 0xffff); p1[3] = (unsigned short)(hi.u >> 16); }
        { unsigned short* p3 = (unsigned short*)(L + 3 * SLOT + 2 + wb);
          p3[0] = (unsigned short)(lo.u & 0xffff); p3[1] = (unsigned short)(lo.u >> 16);
          p3[2] = (unsigned short)(hi.u & 0xffff); p3[3] = (unsigned short)(hi.u >> 16); }
    }

    const int lane = tid & 63;
    const int wv   = tid >> 6;      // wave -> output rows h0+4wv .. h0+4wv+3
    const int kg   = lane >> 4;
    const int ml   = lane & 15;     // channel (B/D col) AND A-row (w-pos)
    const int s    = ml & 3;
    const int cbs  = s * SLOT + ((8 - 2 * s) & 7);   // phase-copy base

    // ---- B fragments (4 mfma) ----
    half8v bf[4];
#pragma unroll
    for (int m = 0; m < 4; m++) {
        union { uint4 u; half8v h; } bb;
        bb.u = *(const uint4*)(wB2 + (((m * 16 + ml) * 4) + kg) * 8);
        bf[m] = bb.h;
    }

    // ---- per-lane A quad base byte-offsets: ab[m][q] ----
    int ab[4][2];
#pragma unroll
    for (int m = 0; m < 4; m++) {
#pragma unroll
        for (int q = 0; q < 2; q++) {
            int r = m * 8 + kg * 2 + q;
            if (r > 26) r = 26;                  // dead rows (weights 0)
            const int p  = (r * 11) >> 5;        // r/3 for r<32
            const int kh = r - 3 * p;
            ab[m][q] = cbs + (p * SROWS + wv * 4 + kh) * 72 + 2 * ml;
        }
    }

    __syncthreads();

    f32x4 acc[4][2];
#pragma unroll
    for (int t = 0; t < 4; t++) {
        acc[t][0] = f32x4{0.f, 0.f, 0.f, 0.f};
        acc[t][1] = f32x4{0.f, 0.f, 0.f, 0.f};
    }

    // ---- 8 tiles x 4 mfma; 8 ds_read_b64 per tile, immediate offsets ----
#pragma unroll
    for (int th = 0; th < 4; th++) {
#pragma unroll
        for (int hf = 0; hf < 2; hf++) {
            const int off = th * 72 + hf * 32;
#pragma unroll
            for (int m = 0; m < 4; m++) {
                const uint2 q0 = *(const uint2*)(L + ab[m][0] + off);
                const uint2 q1 = *(const uint2*)(L + ab[m][1] + off);
                union { unsigned int u[4]; half8v h; } af;
                af.u[0] = q0.x; af.u[1] = q0.y;
                af.u[2] = q1.x; af.u[3] = q1.y;
                acc[th][hf] = __builtin_amdgcn_mfma_f32_16x16x32_f16(
                    af.h, bf[m], acc[th][hf], 0, 0, 0);
            }
        }
    }

    // ---- epilogue: bias+mult fold, stats, y store (channel-major) ----
    const float bv = cb[ml];
    const float mv = mult[ml];
    float ssum = 0.0f, ssq = 0.0f;
#pragma unroll
    for (int th = 0; th < 4; th++) {
#pragma unroll
        for (int hf = 0; hf < 2; hf++) {
            const f32x4 a = acc[th][hf];
            const float o0 = (a[0] + bv) * mv;
            const float o1 = (a[1] + bv) * mv;
            const float o2 = (a[2] + bv) * mv;
            const float o3 = (a[3] + bv) * mv;
            ssum += (o0 + o1) + (o2 + o3);
            ssq  += (o0 * o0 + o1 * o1) + (o2 * o2 + o3 * o3);
            const size_t yi = ((size_t)(b * OCH + ml) * OD + d) * (OH * OW)
                            + (size_t)(h0 + wv * 4 + th) * OW + hf * 16 + kg * 4;
            union { fp16x2 h; unsigned int u; } p01, p23;
            p01.h = __builtin_amdgcn_cvt_pkrtz(o0, o1);
            p23.h = __builtin_amdgcn_cvt_pkrtz(o2, o3);
            uint2 pk; pk.x = p01.u; pk.y = p23.u;
            *(uint2*)&y[yi] = pk;
        }
    }

    // reduce lanes sharing a channel (lane ^16, ^32)
    ssum += __shfl_xor(ssum, 16); ssum += __shfl_xor(ssum, 32);
    ssq  += __shfl_xor(ssq, 16);  ssq  += __shfl_xor(ssq, 32);
    if (lane < 16) { wsum[wv][ml] = ssum; wsq[wv][ml] = ssq; }
    __syncthreads();
    if (tid < OCH) {
        float sA = 0.0f, qA = 0.0f;
#pragma unroll
        for (int k = 0; k < 4; k++) { sA += wsum[k][tid]; qA += wsq[k][tid]; }
        const int sbase = (((b * OD + d) * 2 + half) * OCH + tid) * 2;
        stats[sbase + 0] = sA;
        stats[sbase + 1] = qA;
    }
}

// ===== per-(b,c) norm params: {A = rs*m, B = -mean*rs*m, L = -|m|, H = +|m|}
__global__ void params_kernel(const float* __restrict__ stats,
                              const float* __restrict__ mult,
                              float4* __restrict__ prm)
{
    const int i = blockIdx.x * 256 + threadIdx.x;   // (b,c) pair
    if (i < NB * OCH) {
        const int b = i >> 4, c = i & 15;
        float s = 0.0f, q = 0.0f;
        for (int k = 0; k < OD * 2; k++) {          // 16 d x 2 half
            s += stats[((b * OD * 2 + k) * OCH + c) * 2 + 0];
            q += stats[((b * OD * 2 + k) * OCH + c) * 2 + 1];
        }
        const float mean = s * (1.0f / (float)SPATIAL);
        float var = q * (1.0f / (float)SPATIAL) - mean * mean;
        var = fmaxf(var, 0.0f);
        const float rs = rsqrtf(var + EPSV);
        const float m  = mult[c];
        float4 p;
        p.x = rs * m;             // A
        p.y = -mean * rs * m;     // B
        p.z = -fabsf(m);          // L
        p.w =  fabsf(m);          // H
        prm[i] = p;
    }
}

// ===== norm_max (R1 version, measured ~11us = BW roofline; do not touch).
__global__ __launch_bounds__(256, 4) void norm_max_kernel(
    const unsigned short* __restrict__ y, const float4* __restrict__ prm,
    float* __restrict__ out)
{
    const int blk = blockIdx.x;     // NB*8 = 1024
    const int b   = blk >> 3;
    const int seg = blk & 7;
    const int tid = threadIdx.x;

    const int s = seg * 2048 + tid * 8;                  // 8 positions
    const unsigned short* yb = y + (size_t)b * OCH * SPATIAL + s;

    uint4 v[OCH];
#pragma unroll
    for (int c = 0; c < OCH; c++) {
        v[c] = *(const uint4*)(yb + (size_t)c * SPATIAL);
    }

    const float4* pb = prm + b * OCH;

    float mx[8];
#pragma unroll
    for (int j = 0; j < 8; j++) mx[j] = -INFINITY;

#pragma unroll
    for (int c = 0; c < OCH; c++) {
        const float4 p = pb[c];          // wave-uniform addr
        const float A = p.x, Bv = p.y, L = p.z, H = p.w;
        union { uint4 u4; unsigned int u[4]; } vv; vv.u4 = v[c];
#pragma unroll
        for (int w = 0; w < 4; w++) {
            union { unsigned int u; __fp16 h[2]; } a; a.u = vv.u[w];
            float f0 = fmaf((float)a.h[0], A, Bv);
            float f1 = fmaf((float)a.h[1], A, Bv);
            f0 = fminf(fmaxf(f0, L), H);                 // v_med3_f32 idiom
            f1 = fminf(fmaxf(f1, L), H);
            mx[2 * w]     = fmaxf(mx[2 * w],     f0);
            mx[2 * w + 1] = fmaxf(mx[2 * w + 1], f1);
        }
    }

    float* ob = out + (size_t)b * SPATIAL + s;
    float4 o0, o1;
    o0.x = mx[0]; o0.y = mx[1]; o0.z = mx[2]; o0.w = mx[3];
    o1.x = mx[4]; o1.y = mx[5]; o1.z = mx[6]; o1.w = mx[7];
    *(float4*)ob       = o0;
    *(float4*)(ob + 4) = o1;
}

extern "C" void kernel_launch(void* const* d_in, const int* in_sizes, int n_in,
                              void* d_out, int out_size, void* d_ws, size_t ws_size,
                              hipStream_t stream) {
    const float* x    = (const float*)d_in[0];
    const float* cw   = (const float*)d_in[1];
    const float* cb   = (const float*)d_in[2];
    const float* mult = (const float*)d_in[3];
    float* out = (float*)d_out;

    // ws: y fp16 channel-major (64 MB) | stats (512 KB) | prm (32 KB) | wB2 (4 KB)
    unsigned short* y = (unsigned short*)d_ws;
    float* stats = (float*)((char*)d_ws + (size_t)NB * OCH * SPATIAL * sizeof(unsigned short));
    float4* prm  = (float4*)(stats + NB * OD * 2 * OCH * 2);
    unsigned short* wB2p = (unsigned short*)(prm + NB * OCH);

    transpose_w_kernel<<<8, 256, 0, stream>>>(cw, wB2p);
    conv_stats_kernel<<<NB * OD * 2, 256, 0, stream>>>(x, wB2p, cb, mult, y, stats);
    params_kernel<<<8, 256, 0, stream>>>(stats, mult, prm);
    norm_max_kernel<<<NB * 8, 256, 0, stream>>>(y, prm, out);
}

// Round 10
// 137.740 us; speedup vs baseline: 1.0944x; 1.0944x over previous
//
#include <hip/hip_runtime.h>
#include <hip/hip_bf16.h>
#include <math.h>

#define ICH   3
#define OCH   16
#define ID    18
#define IH    34
#define IW    34
#define OD    16
#define OH    32
#define OW    32
#define NB    128
#define SPATIAL  (OD * OH * OW)     // 16384 per (b,c)
#define EPSV     1e-5f

typedef __fp16 fp16x2 __attribute__((ext_vector_type(2)));

// Budget (R3-R9): conv VALU busy ~40us = non-MFMA MAC floor (fp32 fma /
// fdot2 / pk_fma agree); MFMA conv LOSES (R8: u16-gather LDS-bound 70us;
// R9: wide-gather staging cost 70us) -> abandoned. norm 11us = BW roofline.
// Fixed harness ~65us. conv idle ~20us is occupancy-independent (R4) and
// prefetch-independent (R7). This round tests the LAST theory: I$ pressure
// (R5 body ~28KB vs 32KB I$; every code-size increase regressed, R6/R7).
// Change: ROLL the K-loop (4 iters x 3 row-pairs + tail) -> ~8KB hot code.
// If neutral -> R5 structure is the ceiling; revert and declare.

// Pre-pass: pack weights into fp16 row-pairs: wp[p][kw][c] = (w[2p],w[2p+1])
// where row r = ic*9 + kd*3 + kh (0..26), r=27 -> 0. u32-packed half2.
__global__ void transpose_w_kernel(const float* __restrict__ cw,
                                   unsigned int* __restrict__ wp) {
    const int i = blockIdx.x * 256 + threadIdx.x;   // 0..671
    if (i < 14 * 48) {
        const int p = i / 48, rem = i - p * 48;
        const int kw = rem >> 4, c = rem & 15;
        const int r0 = 2 * p, r1 = 2 * p + 1;
        // cw is OIDHW: [oc][ic][kd][kh][kw]
        const int ic0 = r0 / 9, kd0 = (r0 / 3) % 3, kh0 = r0 % 3;
        float f0 = cw[((c * ICH + ic0) * 3 + kd0) * 9 + kh0 * 3 + kw];
        float f1 = 0.0f;
        if (r1 < 27) {
            const int ic1 = r1 / 9, kd1 = (r1 / 3) % 3, kh1 = r1 % 3;
            f1 = cw[((c * ICH + ic1) * 3 + kd1) * 9 + kh1 * 3 + kw];
        }
        fp16x2 hv; hv.x = (__fp16)f0; hv.y = (__fp16)f1;
        union { fp16x2 h; unsigned int u; } uu; uu.h = hv;
        wp[i] = uu.u;
    }
}

// ===== conv v16: R5 fdot2 math, ROLLED K-loop. 4 runtime iterations, each
// handling groups 2gp,2gp+1 (6 rows -> row-pairs 3gp..3gp+2, no carry),
// tail = rows 24..26 (pairs 12,13). All intra-body indices compile-time.
// Do NOT: LDS-stage x (R1-R9), MFMA im2col (R8/R9: gather cost > MAC save),
// occupancy pushes (R4), channel-last y (R2), pk_fma_f16 (R6), reg
// prefetch/XCD remap (R7).
__global__ __launch_bounds__(256, 2) void conv_stats_kernel(
    const float* __restrict__ x, const unsigned int* __restrict__ wp,
    const float* __restrict__ cb, const float* __restrict__ mult,
    unsigned short* __restrict__ y, float* __restrict__ stats)
{
    __shared__ float wsum[4][OCH], wsq[4][OCH];

    const int blk = blockIdx.x;
    const int b = blk >> 4;
    const int d = blk & 15;
    const int tid = threadIdx.x;

    const int h  = tid >> 3;        // 0..31
    const int wq = (tid & 7) << 2;  // 0,4,...,28

    float acc[OCH][4];
#pragma unroll
    for (int c = 0; c < OCH; c++) {
        const float bv = cb[c];
        acc[c][0] = bv; acc[c][1] = bv; acc[c][2] = bv; acc[c][3] = bv;
    }

    // load the 3 rows of group g into dst_[3][6]
#define LOADG3(dst_, g_)                                                    \
    {                                                                       \
        const int ic_ = (g_) / 3, kd_ = (g_) % 3;                           \
        const float* plane_ = x + ((size_t)(b * ICH + ic_) * ID + (d + kd_)) * (IH * IW); \
        _Pragma("unroll")                                                   \
        for (int kh_ = 0; kh_ < 3; kh_++) {                                 \
            const float* row_ = plane_ + (size_t)(h + kh_) * IW + wq;       \
            const float4 v0_ = *(const float4*)row_;                        \
            const float2 v1_ = *(const float2*)(row_ + 4);                  \
            dst_[kh_][0] = v0_.x; dst_[kh_][1] = v0_.y;                     \
            dst_[kh_][2] = v0_.z; dst_[kh_][3] = v0_.w;                     \
            dst_[kh_][4] = v1_.x; dst_[kh_][5] = v1_.y;                     \
        }                                                                   \
    }

    // one row-pair (float rows A_,B_): pack 6 cols as (A,B) fp16 pairs, then
    // 3kw x 16c x 4out fdot2 against paired weights wp[p_] (p_ may be runtime).
#define PAIRF(A_, B_, p_)                                                   \
    {                                                                       \
        fp16x2 pk_[6];                                                      \
        _Pragma("unroll")                                                   \
        for (int j_ = 0; j_ < 6; j_++)                                      \
            pk_[j_] = __builtin_amdgcn_cvt_pkrtz((A_)[j_], (B_)[j_]);       \
        const unsigned int* wg_ = wp + (p_) * 48;                           \
        _Pragma("unroll")                                                   \
        for (int kw_ = 0; kw_ < 3; kw_++) {                                 \
            _Pragma("unroll")                                               \
            for (int c_ = 0; c_ < OCH; c_++) {                              \
                union { unsigned int u; fp16x2 h; } wv_;                    \
                wv_.u = wg_[kw_ * OCH + c_];                                \
                acc[c_][0] = __builtin_amdgcn_fdot2(pk_[kw_ + 0], wv_.h, acc[c_][0], false); \
                acc[c_][1] = __builtin_amdgcn_fdot2(pk_[kw_ + 1], wv_.h, acc[c_][1], false); \
                acc[c_][2] = __builtin_amdgcn_fdot2(pk_[kw_ + 2], wv_.h, acc[c_][2], false); \
                acc[c_][3] = __builtin_amdgcn_fdot2(pk_[kw_ + 3], wv_.h, acc[c_][3], false); \
            }                                                               \
        }                                                                   \
    }

#pragma unroll 1
    for (int gp = 0; gp < 4; gp++) {          // rolled: ~8KB hot code
        const int g0 = 2 * gp, g1 = 2 * gp + 1;
        float e[3][6], o[3][6];
        LOADG3(e, g0)
        LOADG3(o, g1)
        PAIRF(e[0], e[1], 3 * gp + 0)         // rows 6gp,   6gp+1
        PAIRF(e[2], o[0], 3 * gp + 1)         // rows 6gp+2, 6gp+3
        PAIRF(o[1], o[2], 3 * gp + 2)         // rows 6gp+4, 6gp+5
    }
    {   // tail: group 8 (rows 24..26), pairs 12 and 13 (row26 + zero row)
        float t[3][6], rz[6];
        LOADG3(t, 8)
#pragma unroll
        for (int j = 0; j < 6; j++) rz[j] = 0.0f;
        PAIRF(t[0], t[1], 12)
        PAIRF(t[2], rz, 13)
    }
#undef PAIRF
#undef LOADG3

    // ---- multiplier fold, stats, fp16 store (channel-major, uint2) ----
    float ssum[OCH], ssq[OCH];
#pragma unroll
    for (int c = 0; c < OCH; c++) {
        const float m = mult[c];
        const float o0 = acc[c][0] * m, o1 = acc[c][1] * m;
        const float o2 = acc[c][2] * m, o3 = acc[c][3] * m;
        ssum[c] = (o0 + o1) + (o2 + o3);
        ssq[c]  = (o0 * o0 + o1 * o1) + (o2 * o2 + o3 * o3);
        const size_t yi = ((size_t)(b * OCH + c) * OD + d) * (OH * OW) + h * OW + wq;
        union { fp16x2 h; unsigned int u; } p01, p23;
        p01.h = __builtin_amdgcn_cvt_pkrtz(o0, o1);
        p23.h = __builtin_amdgcn_cvt_pkrtz(o2, o3);
        uint2 pk; pk.x = p01.u; pk.y = p23.u;
        *(uint2*)&y[yi] = pk;
    }

    // ---- block reduction of stats, per-block partial write (no atomics) ----
#pragma unroll
    for (int c = 0; c < OCH; c++) {
        for (int off = 32; off > 0; off >>= 1) {
            ssum[c] += __shfl_down(ssum[c], off);
            ssq[c]  += __shfl_down(ssq[c], off);
        }
    }
    const int wave = tid >> 6, lane = tid & 63;
    if (lane == 0) {
#pragma unroll
        for (int c = 0; c < OCH; c++) { wsum[wave][c] = ssum[c]; wsq[wave][c] = ssq[c]; }
    }
    __syncthreads();
    if (tid < OCH) {
        float s = 0.0f, q2 = 0.0f;
#pragma unroll
        for (int k = 0; k < 4; k++) { s += wsum[k][tid]; q2 += wsq[k][tid]; }
        const int sbase = ((b * OD + d) * OCH + tid) * 2;
        stats[sbase + 0] = s;
        stats[sbase + 1] = q2;
    }
}

// ===== per-(b,c) norm params: {A = rs*m, B = -mean*rs*m, L = -|m|, H = +|m|}
__global__ void params_kernel(const float* __restrict__ stats,
                              const float* __restrict__ mult,
                              float4* __restrict__ prm)
{
    const int i = blockIdx.x * 256 + threadIdx.x;   // (b,c) pair
    if (i < NB * OCH) {
        const int b = i >> 4, c = i & 15;
        float s = 0.0f, q = 0.0f;
        for (int dd = 0; dd < OD; dd++) {
            s += stats[((b * OD + dd) * OCH + c) * 2 + 0];
            q += stats[((b * OD + dd) * OCH + c) * 2 + 1];
        }
        const float mean = s * (1.0f / (float)SPATIAL);
        float var = q * (1.0f / (float)SPATIAL) - mean * mean;
        var = fmaxf(var, 0.0f);
        const float rs = rsqrtf(var + EPSV);
        const float m  = mult[c];
        float4 p;
        p.x = rs * m;             // A
        p.y = -mean * rs * m;     // B
        p.z = -fabsf(m);          // L
        p.w =  fabsf(m);          // H
        prm[i] = p;
    }
}

// ===== norm_max (R1 version, measured ~11us = BW roofline; do not touch).
__global__ __launch_bounds__(256, 4) void norm_max_kernel(
    const unsigned short* __restrict__ y, const float4* __restrict__ prm,
    float* __restrict__ out)
{
    const int blk = blockIdx.x;     // NB*8 = 1024
    const int b   = blk >> 3;
    const int seg = blk & 7;
    const int tid = threadIdx.x;

    const int s = seg * 2048 + tid * 8;                  // 8 positions
    const unsigned short* yb = y + (size_t)b * OCH * SPATIAL + s;

    uint4 v[OCH];
#pragma unroll
    for (int c = 0; c < OCH; c++) {
        v[c] = *(const uint4*)(yb + (size_t)c * SPATIAL);
    }

    const float4* pb = prm + b * OCH;

    float mx[8];
#pragma unroll
    for (int j = 0; j < 8; j++) mx[j] = -INFINITY;

#pragma unroll
    for (int c = 0; c < OCH; c++) {
        const float4 p = pb[c];          // wave-uniform addr
        const float A = p.x, Bv = p.y, L = p.z, H = p.w;
        union { uint4 u4; unsigned int u[4]; } vv; vv.u4 = v[c];
#pragma unroll
        for (int w = 0; w < 4; w++) {
            union { unsigned int u; __fp16 h[2]; } a; a.u = vv.u[w];
            float f0 = fmaf((float)a.h[0], A, Bv);
            float f1 = fmaf((float)a.h[1], A, Bv);
            f0 = fminf(fmaxf(f0, L), H);                 // v_med3_f32 idiom
            f1 = fminf(fmaxf(f1, L), H);
            mx[2 * w]     = fmaxf(mx[2 * w],     f0);
            mx[2 * w + 1] = fmaxf(mx[2 * w + 1], f1);
        }
    }

    float* ob = out + (size_t)b * SPATIAL + s;
    float4 o0, o1;
    o0.x = mx[0]; o0.y = mx[1]; o0.z = mx[2]; o0.w = mx[3];
    o1.x = mx[4]; o1.y = mx[5]; o1.z = mx[6]; o1.w = mx[7];
    *(float4*)ob       = o0;
    *(float4*)(ob + 4) = o1;
}

extern "C" void kernel_launch(void* const* d_in, const int* in_sizes, int n_in,
                              void* d_out, int out_size, void* d_ws, size_t ws_size,
                              hipStream_t stream) {
    const float* x    = (const float*)d_in[0];
    const float* cw   = (const float*)d_in[1];
    const float* cb   = (const float*)d_in[2];
    const float* mult = (const float*)d_in[3];
    float* out = (float*)d_out;

    // ws: y fp16 channel-major (64 MB) | stats partials (256 KB) | prm (8 KB) | wp (2.7 KB)
    unsigned short* y = (unsigned short*)d_ws;
    float* stats = (float*)((char*)d_ws + (size_t)NB * OCH * SPATIAL * sizeof(unsigned short));
    float4* prm  = (float4*)(stats + NB * OD * OCH * 2);
    unsigned int* wpk = (unsigned int*)(prm + NB * OCH);

    transpose_w_kernel<<<3, 256, 0, stream>>>(cw, wpk);
    conv_stats_kernel<<<NB * 16, 256, 0, stream>>>(x, wpk, cb, mult, y, stats);
    params_kernel<<<8, 256, 0, stream>>>(stats, mult, prm);
    norm_max_kernel<<<NB * 8, 256, 0, stream>>>(y, prm, out);
}